// Round 1
// baseline (107.098 us; speedup 1.0000x reference)
//
#include <hip/hip_runtime.h>

#define BATCH 8
#define NPTS 4096
#define KSEL 5          // K_NN; self-candidate excluded in-scan (see below)
#define ALPHA 1.05f
#define NSEG 16         // candidate-scan split per point (one wave each)
#define SEGLEN (NPTS / NSEG)   // 256
#define TPB (NSEG * 64)        // 1024 threads

// Non-negative IEEE floats order identically to their uint bit patterns.
static __device__ __forceinline__ unsigned min3u(unsigned a, unsigned b, unsigned c) {
  unsigned d;
  asm("v_min3_u32 %0, %1, %2, %3" : "=v"(d) : "v"(a), "v"(b), "v"(c));
  return d;
}
static __device__ __forceinline__ unsigned med3u(unsigned a, unsigned b, unsigned c) {
  unsigned d;
  asm("v_med3_u32 %0, %1, %2, %3" : "=v"(d) : "v"(a), "v"(b), "v"(c));
  return d;
}
static __device__ __forceinline__ unsigned max3u(unsigned a, unsigned b, unsigned c) {
  unsigned d;
  asm("v_max3_u32 %0, %1, %2, %3" : "=v"(d) : "v"(a), "v"(b), "v"(c));
  return d;
}
static __device__ __forceinline__ unsigned umn(unsigned a, unsigned b) { return a < b ? a : b; }
static __device__ __forceinline__ unsigned umx(unsigned a, unsigned b) { return a > b ? a : b; }

#define FINF 0x7F800000u   // +inf bit pattern

// Packed dual-FP32 math (gfx90a+ VOP3P: v_pk_{add,mul,fma}_f32, register pairs).
// MI355X 157.3 TF FP32 spec rate == the packed rate; scalar f32 is half that.
// Each op is two independent IEEE f32 ops with identical rounding to the scalar
// instruction -> bit-exact vs the scalar sequence.
typedef float v2f __attribute__((ext_vector_type(2)));

static __device__ __forceinline__ v2f pk_add(v2f a, v2f b) {
  v2f d;
  asm("v_pk_add_f32 %0, %1, %2" : "=v"(d) : "v"(a), "v"(b));
  return d;
}
static __device__ __forceinline__ v2f pk_mul(v2f a, v2f b) {
  v2f d;
  asm("v_pk_mul_f32 %0, %1, %2" : "=v"(d) : "v"(a), "v"(b));
  return d;
}
static __device__ __forceinline__ v2f pk_fma(v2f a, v2f b, v2f c) {
  v2f d;
  asm("v_pk_fma_f32 %0, %1, %2, %3" : "=v"(d) : "v"(a), "v"(b), "v"(c));
  return d;
}

// Fused branchless insert of two candidates into sorted m[0..KSEL-1].
// Per level {m[k],tA,tB} -> min3 stays, {med3,max3} propagate. Bit-identical
// to sequential insert (absmax 0.0 across prior rounds).
static __device__ __forceinline__ void insert2(unsigned m[KSEL], unsigned tA, unsigned tB) {
#pragma unroll
  for (int k = 0; k < KSEL - 1; ++k) {
    const unsigned mk = m[k];
    m[k] = min3u(mk, tA, tB);
    const unsigned nA = med3u(mk, tA, tB);
    const unsigned nB = max3u(mk, tA, tB);
    tA = nA;
    tB = nB;
  }
  m[KSEL - 1] = min3u(m[KSEL - 1], tA, tB);
}

// Segment scan. EXCL=true for the single wave whose candidate range contains
// the tile's own point indices: the self-distance (exactly 0.0, always the
// global min since all other pairwise distances are > 0 for distinct points)
// is replaced by +inf so a 5-deep list suffices. Distances are computed as
// (x_j - x_i) via pk_add(x_j, -x_i); RN is sign-symmetric so squares/fmas are
// bit-identical to the previous (x_i - x_j) scalar form.
template <bool EXCL>
static __device__ __forceinline__ void scan_seg(const float* __restrict__ xs,
                                                const float* __restrict__ ys,
                                                const float* __restrict__ zs,
                                                const int j0, const int i,
                                                const v2f nx2, const v2f ny2, const v2f nz2,
                                                unsigned m[KSEL]) {
#pragma unroll 4
  for (int jj = 0; jj < SEGLEN; jj += 4) {
    // 4 wave-uniform candidates: 3x ds_read_b128 broadcast, immediate offsets
    const float4 cx = *(const float4*)&xs[j0 + jj];
    const float4 cy = *(const float4*)&ys[j0 + jj];
    const float4 cz = *(const float4*)&zs[j0 + jj];

    const v2f cxAB = {cx.x, cx.y}, cxCD = {cx.z, cx.w};
    const v2f cyAB = {cy.x, cy.y}, cyCD = {cy.z, cy.w};
    const v2f czAB = {cz.x, cz.y}, czCD = {cz.z, cz.w};

    const v2f dx0 = pk_add(cxAB, nx2);
    const v2f dx1 = pk_add(cxCD, nx2);
    const v2f dy0 = pk_add(cyAB, ny2);
    const v2f dy1 = pk_add(cyCD, ny2);
    const v2f dz0 = pk_add(czAB, nz2);
    const v2f dz1 = pk_add(czCD, nz2);

    v2f d0 = pk_mul(dx0, dx0);
    v2f d1 = pk_mul(dx1, dx1);
    d0 = pk_fma(dy0, dy0, d0);
    d1 = pk_fma(dy1, dy1, d1);
    d0 = pk_fma(dz0, dz0, d0);
    d1 = pk_fma(dz1, dz1, d1);

    unsigned uA = __float_as_uint(d0.x);
    unsigned uB = __float_as_uint(d0.y);
    unsigned uC = __float_as_uint(d1.x);
    unsigned uD = __float_as_uint(d1.y);
    if (EXCL) {
      const int jb = j0 + jj;
      if (jb + 0 == i) uA = FINF;
      if (jb + 1 == i) uB = FINF;
      if (jb + 2 == i) uC = FINF;
      if (jb + 3 == i) uD = FINF;
    }

    insert2(m, uA, uB);
    insert2(m, uC, uD);
  }
}

// ---------------------------------------------------------------------------
// Kernel 1: per-point mean 5-NN squared distance.
// grid = BATCH * (NPTS/64) = 512 blocks, block = 1024 threads (16 waves).
// VALU-bound (97% busy): distance math packed 2-wide (24->12 ops / 4 cand),
// selection list shrunk 6->5 via exact in-scan self-exclusion (32->26 ops).
// ---------------------------------------------------------------------------
__global__ __launch_bounds__(TPB) void knn_value_kernel(const float* __restrict__ pc,
                                                        float* __restrict__ value,
                                                        float* __restrict__ out) {
  __shared__ union __align__(16) {
    struct { float xs[NPTS]; float ys[NPTS]; float zs[NPTS]; } s;  // 48 KB
    unsigned cand[NSEG][64][KSEL];                                 // 20 KB
  } sh;

  const int tid = threadIdx.x;
  const int pt  = tid & 63;
  const int seg = __builtin_amdgcn_readfirstlane(tid >> 6);  // wave-uniform
  const int b    = blockIdx.x >> 6;
  const int tile = blockIdx.x & 63;
  const int i    = tile * 64 + pt;

  if (blockIdx.x == 0 && tid == 0) out[0] = 0.0f;  // stats kernel accumulates

  const float* __restrict__ base = pc + (size_t)b * (NPTS * 3);

  // Stage batch point cloud into LDS (SoA). 4 points per thread.
#pragma unroll
  for (int p = 0; p < NPTS / TPB; ++p) {
    const int idx = tid + p * TPB;
    sh.s.xs[idx] = base[idx * 3 + 0];
    sh.s.ys[idx] = base[idx * 3 + 1];
    sh.s.zs[idx] = base[idx * 3 + 2];
  }
  __syncthreads();

  const float xi = sh.s.xs[i];
  const float yi = sh.s.ys[i];
  const float zi = sh.s.zs[i];
  const v2f nx2 = {-xi, -xi};
  const v2f ny2 = {-yi, -yi};
  const v2f nz2 = {-zi, -zi};

  unsigned m[KSEL];
#pragma unroll
  for (int k = 0; k < KSEL; ++k) m[k] = FINF;

  const int j0 = seg * SEGLEN;
  // The tile's own 64 point indices [tile*64, tile*64+64) all fall inside the
  // single segment seg == tile>>2 (SEGLEN=256). Only that wave pays the
  // per-candidate exclusion compare.
  if (seg == (tile >> 2)) {
    scan_seg<true>(sh.s.xs, sh.s.ys, sh.s.zs, j0, i, nx2, ny2, nz2, m);
  } else {
    scan_seg<false>(sh.s.xs, sh.s.ys, sh.s.zs, j0, i, nx2, ny2, nz2, m);
  }
  __syncthreads();  // everyone done reading the stage buffer

#pragma unroll
  for (int k = 0; k < KSEL; ++k) sh.cand[seg][pt][k] = m[k];
  __syncthreads();

  // Tree-merge the 16 sorted lists per point: 8,4,2,1 pairwise merges.
  for (int st = 1; st < NSEG; st <<= 1) {
    const int pairs = NSEG / (2 * st);
    if (tid < pairs * 64) {
      const int q = tid >> 6;
      const int p = tid & 63;
      unsigned* A = &sh.cand[2 * st * q][p][0];
      const unsigned* B = &sh.cand[2 * st * q + st][p][0];
      unsigned mm[KSEL];
#pragma unroll
      for (int k = 0; k < KSEL; ++k) mm[k] = A[k];
#pragma unroll
      for (int k = 0; k < KSEL; ++k) {
        unsigned t = B[k];
#pragma unroll
        for (int u = 0; u < KSEL - 1; ++u) {
          const unsigned lo = umn(mm[u], t);
          t = umx(mm[u], t);
          mm[u] = lo;
        }
        mm[KSEL - 1] = umn(mm[KSEL - 1], t);
      }
#pragma unroll
      for (int k = 0; k < KSEL; ++k) A[k] = mm[k];
    }
    __syncthreads();
  }

  // Self already excluded: mean of the 5 smallest real-neighbor distances,
  // summed ascending (same value order as the previous k=1..5 sum).
  if (tid < 64) {
    float s5 = 0.f;
#pragma unroll
    for (int k = 0; k < KSEL; ++k) s5 += __uint_as_float(sh.cand[0][tid][k]);
    value[b * NPTS + tile * 64 + tid] = s5 * 0.2f;
  }
}

// ---------------------------------------------------------------------------
// Kernel 2: per-batch mean / unbiased std / threshold / masked mean * weight,
// then atomicAdd of loss*(1/BATCH) into out (zeroed by kernel 1).
// grid = 8 blocks, block = 256 threads. UNCHANGED (bit-exact output).
// ---------------------------------------------------------------------------
__global__ __launch_bounds__(256) void stats_kernel(const float* __restrict__ value,
                                                    const float* __restrict__ weights,
                                                    float* __restrict__ out) {
  __shared__ float red[256];
  const int b   = blockIdx.x;
  const int tid = threadIdx.x;
  const float* __restrict__ v = value + b * NPTS;

  // pass 1: mean
  float s = 0.f;
  for (int j = tid; j < NPTS; j += 256) s += v[j];
  red[tid] = s;
  __syncthreads();
  for (int off = 128; off > 0; off >>= 1) {
    if (tid < off) red[tid] += red[tid + off];
    __syncthreads();
  }
  const float mean = red[0] * (1.0f / NPTS);
  __syncthreads();

  // pass 2: unbiased std
  float s2 = 0.f;
  for (int j = tid; j < NPTS; j += 256) {
    const float d = v[j] - mean;
    s2 += d * d;
  }
  red[tid] = s2;
  __syncthreads();
  for (int off = 128; off > 0; off >>= 1) {
    if (tid < off) red[tid] += red[tid + off];
    __syncthreads();
  }
  const float thr = mean + ALPHA * sqrtf(red[0] * (1.0f / (NPTS - 1)));
  __syncthreads();

  // pass 3: masked sum (strict >)
  float s3 = 0.f;
  for (int j = tid; j < NPTS; j += 256) {
    const float vv = v[j];
    if (vv > thr) s3 += vv;
  }
  red[tid] = s3;
  __syncthreads();
  for (int off = 128; off > 0; off >>= 1) {
    if (tid < off) red[tid] += red[tid + off];
    __syncthreads();
  }
  if (tid == 0) {
    atomicAdd(out, red[0] * (1.0f / NPTS) * weights[b] * (1.0f / BATCH));
  }
}

extern "C" void kernel_launch(void* const* d_in, const int* in_sizes, int n_in,
                              void* d_out, int out_size, void* d_ws, size_t ws_size,
                              hipStream_t stream) {
  const float* pc      = (const float*)d_in[0];   // [8,4096,3] f32
  const float* weights = (const float*)d_in[1];   // [8] f32
  float* out   = (float*)d_out;                   // scalar f32
  float* value = (float*)d_ws;                    // [8*4096] f32

  knn_value_kernel<<<dim3(BATCH * (NPTS / 64)), dim3(TPB), 0, stream>>>(pc, value, out);
  stats_kernel<<<dim3(BATCH), dim3(256), 0, stream>>>(value, weights, out);
}